// Round 8
// baseline (184.565 us; speedup 1.0000x reference)
//
#include <hip/hip_runtime.h>
#include <hip/hip_bf16.h>
#include <stdint.h>

typedef __attribute__((ext_vector_type(8))) short bf16x8;
typedef __attribute__((ext_vector_type(4))) float f32x4;

#define MFMA16(a, b, c) __builtin_amdgcn_mfma_f32_16x16x32_bf16((a), (b), (c), 0, 0, 0)

__device__ __forceinline__ unsigned short f2bf(float f) {
  unsigned int u = __builtin_bit_cast(unsigned int, f);
  unsigned int r = (u + 0x7fffu + ((u >> 16) & 1u)) >> 16;
  return (unsigned short)r;
}

__device__ __forceinline__ void gload16(const unsigned short* g, unsigned short* lds_dst) {
  __builtin_amdgcn_global_load_lds(
      (const __attribute__((address_space(1))) unsigned int*)g,
      (__attribute__((address_space(3))) unsigned int*)lds_dst, 16, 0, 0);
}

// ---------------- f32 -> bf16 conversion ----------------
__global__ void cvt_f32_bf16(const float* __restrict__ in, unsigned short* __restrict__ out, long n) {
  long i = ((long)blockIdx.x * blockDim.x + threadIdx.x) * 4;
  long stride = (long)gridDim.x * blockDim.x * 4;
  for (; i < n; i += stride) {
    float4 v = *(const float4*)(in + i);
    ushort4 o;
    o.x = f2bf(v.x); o.y = f2bf(v.y); o.z = f2bf(v.z); o.w = f2bf(v.w);
    *(ushort4*)(out + i) = o;
  }
}

// ------- 256 x (NB*64) B^T GEMM: balanced grid + counted-vmcnt 4-phase -------
// (r6 config, best measured GEMM so far — unchanged this round)
template <int EPI, int NB>
__global__ __launch_bounds__(512, 2)
void gemm_bt(const unsigned short* __restrict__ A,
             const unsigned short* __restrict__ Bt,
             const float* __restrict__ bias,
             int M, int N, int K,
             unsigned short* __restrict__ q_out,
             unsigned short* __restrict__ k_out,
             unsigned short* __restrict__ vt_out,
             float* __restrict__ f_out) {
  constexpr int BNT = NB * 64;
  alignas(16) __shared__ unsigned short Alds[2][2][128 * 64];
  alignas(16) __shared__ unsigned short Blds[2][BNT * 64];
  const int t = threadIdx.x, w = t >> 6, l = t & 63;
  const int bm = blockIdx.x, bn = blockIdx.y;
  const int wm = w >> 2, wn = w & 3;
  const int lo = l & 15, hi = l >> 4, swk = lo & 7;

  f32x4 acc[8][NB];
  const f32x4 zero = {0.f, 0.f, 0.f, 0.f};
#pragma unroll
  for (int i = 0; i < 8; ++i)
#pragma unroll
    for (int j = 0; j < NB; ++j) acc[i][j] = zero;

  const int sr = t >> 3;
  const int gsrcE = ((t & 7) ^ (sr & 7)) * 8;
  const unsigned short* Asrc = A + (long)(bm * 256 + sr) * K + gsrcE;
  const unsigned short* Bsrc = Bt + (long)(bn * BNT + sr) * K + gsrcE;

#define STAGE_AH(sb, qh, koff) do {                                    \
    unsigned short* d_ = &Alds[sb][qh][w * 512];                       \
    const unsigned short* s_ = Asrc + (long)(qh) * 64 * K + (koff);    \
    gload16(s_, d_); gload16(s_ + 128L * K, d_ + 4096); } while (0)
#define STAGE_B(sb, koff) do {                                         \
    _Pragma("unroll")                                                  \
    for (int c_ = 0; c_ < NB; ++c_)                                    \
      gload16(Bsrc + (long)c_ * 64 * K + (koff),                       \
              &Blds[sb][c_ * 4096 + w * 512]); } while (0)

  STAGE_AH(0, 0, 0);
  STAGE_B(0, 0);
  STAGE_AH(0, 1, 0);
  asm volatile("s_waitcnt vmcnt(2)" ::: "memory");
  __builtin_amdgcn_sched_barrier(0);
  __builtin_amdgcn_s_barrier();

  const int lrA = (wm * 64 + lo) * 64;
  const int lrB = (wn * (NB * 16) + lo) * 64;
  const int gk0 = ((hi) ^ swk) * 8;
  const int gk1 = ((4 + hi) ^ swk) * 8;

  bf16x8 af[4][2], blo[2][2], bhi[2];

  for (int kt = 0; kt < 16; ++kt) {
    const int c = kt & 1, nb = c ^ 1;
    const bool st = (kt < 15);
    const int koff = (kt + 1) * 64;
    const unsigned short* A0 = Alds[c][0];
    const unsigned short* A1 = Alds[c][1];
    const unsigned short* Bs = Blds[c];

    // ==== P1
#pragma unroll
    for (int ii = 0; ii < 4; ++ii) {
      af[ii][0] = *(const bf16x8*)&A0[lrA + ii * 1024 + gk0];
      af[ii][1] = *(const bf16x8*)&A0[lrA + ii * 1024 + gk1];
    }
#pragma unroll
    for (int jj = 0; jj < NB - 1; ++jj) {
      blo[jj][0] = *(const bf16x8*)&Bs[lrB + jj * 1024 + gk0];
      blo[jj][1] = *(const bf16x8*)&Bs[lrB + jj * 1024 + gk1];
    }
    if (st) STAGE_AH(nb, 0, koff);
    __builtin_amdgcn_s_barrier();
    asm volatile("s_waitcnt lgkmcnt(0)" ::: "memory");
    __builtin_amdgcn_sched_barrier(0);
    __builtin_amdgcn_s_setprio(1);
#pragma unroll
    for (int ii = 0; ii < 4; ++ii)
#pragma unroll
      for (int jj = 0; jj < NB - 1; ++jj) {
        acc[ii][jj] = MFMA16(af[ii][0], blo[jj][0], acc[ii][jj]);
        acc[ii][jj] = MFMA16(af[ii][1], blo[jj][1], acc[ii][jj]);
      }
    __builtin_amdgcn_s_setprio(0);
    __builtin_amdgcn_s_barrier();

    // ==== P2
    bhi[0] = *(const bf16x8*)&Bs[lrB + (NB - 1) * 1024 + gk0];
    bhi[1] = *(const bf16x8*)&Bs[lrB + (NB - 1) * 1024 + gk1];
    if (st) STAGE_B(nb, koff);
    __builtin_amdgcn_s_barrier();
    asm volatile("s_waitcnt lgkmcnt(0)" ::: "memory");
    __builtin_amdgcn_sched_barrier(0);
    __builtin_amdgcn_s_setprio(1);
#pragma unroll
    for (int ii = 0; ii < 4; ++ii) {
      acc[ii][NB - 1] = MFMA16(af[ii][0], bhi[0], acc[ii][NB - 1]);
      acc[ii][NB - 1] = MFMA16(af[ii][1], bhi[1], acc[ii][NB - 1]);
    }
    __builtin_amdgcn_s_setprio(0);
    if (st) {
      if constexpr (NB == 3) { asm volatile("s_waitcnt vmcnt(5)" ::: "memory"); }
      else                   { asm volatile("s_waitcnt vmcnt(4)" ::: "memory"); }
    } else {
      asm volatile("s_waitcnt vmcnt(0)" ::: "memory");
    }
    __builtin_amdgcn_sched_barrier(0);
    __builtin_amdgcn_s_barrier();

    // ==== P3
#pragma unroll
    for (int ii = 0; ii < 4; ++ii) {
      af[ii][0] = *(const bf16x8*)&A1[lrA + ii * 1024 + gk0];
      af[ii][1] = *(const bf16x8*)&A1[lrA + ii * 1024 + gk1];
    }
    if (st) STAGE_AH(nb, 1, koff);
    __builtin_amdgcn_s_barrier();
    asm volatile("s_waitcnt lgkmcnt(0)" ::: "memory");
    __builtin_amdgcn_sched_barrier(0);
    __builtin_amdgcn_s_setprio(1);
#pragma unroll
    for (int ii = 0; ii < 4; ++ii) {
      acc[4 + ii][NB - 1] = MFMA16(af[ii][0], bhi[0], acc[4 + ii][NB - 1]);
      acc[4 + ii][NB - 1] = MFMA16(af[ii][1], bhi[1], acc[4 + ii][NB - 1]);
    }
    __builtin_amdgcn_s_setprio(0);
    __builtin_amdgcn_s_barrier();

    // ==== P4
    __builtin_amdgcn_s_setprio(1);
#pragma unroll
    for (int ii = 0; ii < 4; ++ii)
#pragma unroll
      for (int jj = 0; jj < NB - 1; ++jj) {
        acc[4 + ii][jj] = MFMA16(af[ii][0], blo[jj][0], acc[4 + ii][jj]);
        acc[4 + ii][jj] = MFMA16(af[ii][1], blo[jj][1], acc[4 + ii][jj]);
      }
    __builtin_amdgcn_s_setprio(0);
    if (st) {
      asm volatile("s_waitcnt vmcnt(2)" ::: "memory");
      __builtin_amdgcn_sched_barrier(0);
    }
    __builtin_amdgcn_s_barrier();
  }
#undef STAGE_AH
#undef STAGE_B

  // ---- epilogue ----
#pragma unroll
  for (int i = 0; i < 8; ++i) {
#pragma unroll
    for (int j = 0; j < NB; ++j) {
#pragma unroll
      for (int r = 0; r < 4; ++r) {
        int row = bm * 256 + wm * 128 + i * 16 + hi * 4 + r;
        int col = bn * BNT + wn * (NB * 16) + j * 16 + lo;
        float v = acc[i][j][r] + bias[col];
        if (EPI == 0) {
          int b = row >> 11, tt = row & 2047;
          int seg = col >> 10, cc = col & 1023;
          int h = cc >> 6, d = cc & 63;
          long bh = (long)(b * 16 + h);
          // Q pre-scaled by 1/sqrt(64) * log2(e) (softmax runs in exp2 domain)
          if (seg == 0)      q_out[(bh * 2048 + tt) * 64 + d] = f2bf(v * 0.1803368801111f);
          else if (seg == 1) k_out[(bh * 2048 + tt) * 64 + d] = f2bf(v);
          else               vt_out[(bh * 64 + d) * 2048 + tt] = f2bf(v);
        } else {
          f_out[(long)row * N + col] = v;
        }
      }
    }
  }
}

// ---------------- causal flash attention v7: QBLK=32/wave ----------------
// LDS-read-bound before (each wave read the full shared K/V tile to serve only
// 16 q-rows). Now each wave owns 32 q-rows as two 16-row groups: the SAME
// K-frags feed both groups' QK^T and the SAME V-frags feed both PV steps, so
// K/V LDS traffic per q-row HALVES (per-tile b128-equiv 176 -> 224 for 2x rows
// = 1.57x less). Grid: 64 bh x 4 strip-pairs = 256 blocks = exactly 1 round.
// Strips of 256 rows; pair (p, 7-p) -> every block exactly 36 KV tile-steps.
// Max-free softmax (exp2 domain) retained.
__global__ __launch_bounds__(512, 2)
void attn_kernel(const unsigned short* __restrict__ Q,
                 const unsigned short* __restrict__ K,
                 const unsigned short* __restrict__ Vt,
                 unsigned short* __restrict__ Y) {
  alignas(16) __shared__ unsigned short Kbuf[2][64 * 64];
  alignas(16) __shared__ unsigned short Vbuf[2][64 * 64];
  alignas(16) __shared__ unsigned short pbuf[8][32 * 64];
  const int t = threadIdx.x, w = t >> 6, l = t & 63;
  const int lo = l & 15, hi = l >> 4;
  const int bh = blockIdx.x;
  const int p = blockIdx.y;            // 0..3
  const int b = bh >> 4, h = bh & 15;
  const int sA = p, sB = 7 - p;
  const int nA = 4 * p + 4;
  const int nTot = 36;
  const unsigned short* Qp = Q + (long)bh * 2048 * 64;
  const unsigned short* Kp = K + (long)bh * 2048 * 64;
  const unsigned short* Vp = Vt + (long)bh * 64 * 2048;
  unsigned short* pw = pbuf[w];

  const short one_bf = (short)0x3F80;
  const bf16x8 ones = {one_bf, one_bf, one_bf, one_bf, one_bf, one_bf, one_bf, one_bf};
  const f32x4 zero = {0.f, 0.f, 0.f, 0.f};

  const int qbA = sA * 256 + w * 32;
  const int qbB = sB * 256 + w * 32;

  bf16x8 qa0, qa1, qb0, qb1;           // group a: rows qb+lo; group b: rows qb+16+lo
  f32x4 lsA, lsB;
  f32x4 oaccA[4], oaccB[4];

  qa0 = *(const bf16x8*)&Qp[(qbA + lo) * 64 + hi * 8];
  qa1 = *(const bf16x8*)&Qp[(qbA + lo) * 64 + 32 + hi * 8];
  qb0 = *(const bf16x8*)&Qp[(qbA + 16 + lo) * 64 + hi * 8];
  qb1 = *(const bf16x8*)&Qp[(qbA + 16 + lo) * 64 + 32 + hi * 8];
  lsA = zero; lsB = zero;
#pragma unroll
  for (int dg = 0; dg < 4; ++dg) { oaccA[dg] = zero; oaccB[dg] = zero; }

  const int srow = t >> 3;
  const int scw = ((t & 7) ^ (srow & 7)) * 8;
  const int sw = lo & 7;               // row&7 identical for rows lo and 16+lo

#define STAGE(kvoff, bufidx)                                          \
  do {                                                                \
    unsigned short* KB_ = Kbuf[bufidx] + w * 512;                     \
    unsigned short* VB_ = Vbuf[bufidx] + w * 512;                     \
    gload16(Kp + (long)((kvoff) + srow) * 64 + scw, KB_);             \
    gload16(Vp + (long)srow * 2048 + (kvoff) + scw, VB_);             \
  } while (0)

  STAGE(0, 0);
  __syncthreads();

  for (int g = 0; g < nTot; ++g) {
    const bool inA = (g < nA);
    const int kvb = (inA ? g : g - nA) * 64;
    const int cur = g & 1;
    if (g + 1 < nTot) {
      const int jn = (g + 1 < nA) ? g + 1 : g + 1 - nA;
      STAGE(jn * 64, cur ^ 1);
    }
    const int qbase = inA ? qbA : qbB;
    if (kvb <= qbase + 31) {
      const unsigned short* KB = Kbuf[cur];
      const unsigned short* VB = Vbuf[cur];
      // ---- QK^T (swapped): K-frags shared by both q-groups ----
      f32x4 sa[4], sb[4];
#pragma unroll
      for (int cg = 0; cg < 4; ++cg) { sa[cg] = zero; sb[cg] = zero; }
      __builtin_amdgcn_s_setprio(1);
#pragma unroll
      for (int cg = 0; cg < 4; ++cg) {
        bf16x8 k0 = *(const bf16x8*)&KB[(cg * 16 + lo) * 64 + ((hi) ^ sw) * 8];
        bf16x8 k1 = *(const bf16x8*)&KB[(cg * 16 + lo) * 64 + ((4 + hi) ^ sw) * 8];
        sa[cg] = MFMA16(k0, qa0, sa[cg]);
        sa[cg] = MFMA16(k1, qa1, sa[cg]);
        sb[cg] = MFMA16(k0, qb0, sb[cg]);
        sb[cg] = MFMA16(k1, qb1, sb[cg]);
      }
      __builtin_amdgcn_s_setprio(0);
      // mask: k index = kvb + cg*16 + hi*4 + r; q = qbase+lo (a), qbase+16+lo (b)
      if (kvb + 63 > qbase) {
        const int la = qbase + lo - kvb;
        const int lb = la + 16;
#pragma unroll
        for (int cg = 0; cg < 4; ++cg)
#pragma unroll
          for (int r = 0; r < 4; ++r) {
            const int ki = cg * 16 + hi * 4 + r;
            if (ki > la) sa[cg][r] = -__builtin_inff();
            if (ki > lb) sb[cg][r] = -__builtin_inff();
          }
      }
      // ---- max-free softmax numerators ----
#pragma unroll
      for (int cg = 0; cg < 4; ++cg) {
        const int gg = (cg * 2 + (hi >> 1)) ^ sw;
        {
          float p0 = exp2f(sa[cg][0]);
          float p1 = exp2f(sa[cg][1]);
          float p2 = exp2f(sa[cg][2]);
          float p3 = exp2f(sa[cg][3]);
          unsigned int u0, u1;
          asm("v_cvt_pk_bf16_f32 %0, %1, %2" : "=v"(u0) : "v"(p0), "v"(p1));
          asm("v_cvt_pk_bf16_f32 %0, %1, %2" : "=v"(u1) : "v"(p2), "v"(p3));
          uint2 val; val.x = u0; val.y = u1;
          *(uint2*)&pw[lo * 64 + gg * 8 + (hi & 1) * 4] = val;
        }
        {
          float p0 = exp2f(sb[cg][0]);
          float p1 = exp2f(sb[cg][1]);
          float p2 = exp2f(sb[cg][2]);
          float p3 = exp2f(sb[cg][3]);
          unsigned int u0, u1;
          asm("v_cvt_pk_bf16_f32 %0, %1, %2" : "=v"(u0) : "v"(p0), "v"(p1));
          asm("v_cvt_pk_bf16_f32 %0, %1, %2" : "=v"(u1) : "v"(p2), "v"(p3));
          uint2 val; val.x = u0; val.y = u1;
          *(uint2*)&pw[(16 + lo) * 64 + gg * 8 + (hi & 1) * 4] = val;
        }
      }
      asm volatile("s_waitcnt lgkmcnt(0)" ::: "memory");
      // ---- P frags, rowsum, PV: V-frags shared by both q-groups ----
      bf16x8 pA0 = *(const bf16x8*)&pw[lo * 64 + ((hi) ^ sw) * 8];
      bf16x8 pA1 = *(const bf16x8*)&pw[lo * 64 + ((4 + hi) ^ sw) * 8];
      bf16x8 pB0 = *(const bf16x8*)&pw[(16 + lo) * 64 + ((hi) ^ sw) * 8];
      bf16x8 pB1 = *(const bf16x8*)&pw[(16 + lo) * 64 + ((4 + hi) ^ sw) * 8];
      __builtin_amdgcn_s_setprio(1);
      lsA = MFMA16(pA0, ones, lsA);
      lsA = MFMA16(pA1, ones, lsA);
      lsB = MFMA16(pB0, ones, lsB);
      lsB = MFMA16(pB1, ones, lsB);
#pragma unroll
      for (int dg = 0; dg < 4; ++dg) {
        bf16x8 vv0 = *(const bf16x8*)&VB[(dg * 16 + lo) * 64 + ((hi) ^ sw) * 8];
        bf16x8 vv1 = *(const bf16x8*)&VB[(dg * 16 + lo) * 64 + ((4 + hi) ^ sw) * 8];
        oaccA[dg] = MFMA16(pA0, vv0, oaccA[dg]);
        oaccA[dg] = MFMA16(pA1, vv1, oaccA[dg]);
        oaccB[dg] = MFMA16(pB0, vv0, oaccB[dg]);
        oaccB[dg] = MFMA16(pB1, vv1, oaccB[dg]);
      }
      __builtin_amdgcn_s_setprio(0);
    }
    // strip transition: finalize A, re-init for B
    if (g == nA - 1) {
#pragma unroll
      for (int r = 0; r < 4; ++r) {
        float invA = 1.0f / lsA[r];
        float invB = 1.0f / lsB[r];
        int rowgA = qbA + hi * 4 + r;
        long baseA = ((long)b * 2048 + rowgA) * 1024 + h * 64;
        long baseB = baseA + 16 * 1024;
#pragma unroll
        for (int dg = 0; dg < 4; ++dg) {
          Y[baseA + dg * 16 + lo] = f2bf(oaccA[dg][r] * invA);
          Y[baseB + dg * 16 + lo] = f2bf(oaccB[dg][r] * invB);
        }
      }
      qa0 = *(const bf16x8*)&Qp[(qbB + lo) * 64 + hi * 8];
      qa1 = *(const bf16x8*)&Qp[(qbB + lo) * 64 + 32 + hi * 8];
      qb0 = *(const bf16x8*)&Qp[(qbB + 16 + lo) * 64 + hi * 8];
      qb1 = *(const bf16x8*)&Qp[(qbB + 16 + lo) * 64 + 32 + hi * 8];
      lsA = zero; lsB = zero;
#pragma unroll
      for (int dg = 0; dg < 4; ++dg) { oaccA[dg] = zero; oaccB[dg] = zero; }
    }
    __syncthreads();
  }

  // ---- epilogue strip B ----
#pragma unroll
  for (int r = 0; r < 4; ++r) {
    float invA = 1.0f / lsA[r];
    float invB = 1.0f / lsB[r];
    int rowgA = qbB + hi * 4 + r;
    long baseA = ((long)b * 2048 + rowgA) * 1024 + h * 64;
    long baseB = baseA + 16 * 1024;
#pragma unroll
    for (int dg = 0; dg < 4; ++dg) {
      Y[baseA + dg * 16 + lo] = f2bf(oaccA[dg][r] * invA);
      Y[baseB + dg * 16 + lo] = f2bf(oaccB[dg][r] * invB);
    }
  }
#undef STAGE
}

extern "C" void kernel_launch(void* const* d_in, const int* in_sizes, int n_in,
                              void* d_out, int out_size, void* d_ws, size_t ws_size,
                              hipStream_t stream) {
  const float* x      = (const float*)d_in[0];
  const float* w_attn = (const float*)d_in[1];
  const float* b_attn = (const float*)d_in[2];
  const float* w_proj = (const float*)d_in[3];
  const float* b_proj = (const float*)d_in[4];
  float* out = (float*)d_out;

  const long NX = 8192L * 1024;
  const long NWA = 3072L * 1024;
  const long NWP = 1024L * 1024;
  const long NQ = 64L * 2048 * 64;

  char* ws = (char*)d_ws;
  unsigned short* xb  = (unsigned short*)ws; ws += NX * 2;
  unsigned short* wab = (unsigned short*)ws; ws += NWA * 2;
  unsigned short* wpb = (unsigned short*)ws; ws += NWP * 2;
  unsigned short* qb  = (unsigned short*)ws; ws += NQ * 2;
  unsigned short* kb  = (unsigned short*)ws; ws += NQ * 2;
  unsigned short* vtb = (unsigned short*)ws; ws += NQ * 2;
  unsigned short* yb  = (unsigned short*)ws; ws += NX * 2;

  cvt_f32_bf16<<<2048, 256, 0, stream>>>(x, xb, NX);
  cvt_f32_bf16<<<768, 256, 0, stream>>>(w_attn, wab, NWA);
  cvt_f32_bf16<<<256, 256, 0, stream>>>(w_proj, wpb, NWP);

  dim3 g1(32, 16);   // 512 blocks = 2 exact rounds @ 1 block/CU
  gemm_bt<0, 3><<<g1, 512, 0, stream>>>(xb, wab, b_attn, 8192, 3072, 1024,
                                        qb, kb, vtb, nullptr);
  dim3 ga(64, 4);    // 256 blocks = exactly 1 round
  attn_kernel<<<ga, 512, 0, stream>>>(qb, kb, vtb, yb);
  dim3 g2(32, 8);    // 256 blocks = 1 exact round, full machine
  gemm_bt<1, 2><<<g2, 512, 0, stream>>>(yb, wpb, b_proj, 8192, 1024, 1024,
                                        nullptr, nullptr, nullptr, out);
}